// Round 1
// baseline (2401.842 us; speedup 1.0000x reference)
//
#include <hip/hip_runtime.h>
#include <hip/hip_bf16.h>

// Problem constants (AdaptiveMobiusLayer): B=4, S=4096, DIM=1024
#define PB 4
#define PS 4096
#define PD 1024
#define ROWS (PB * PS)          // 16384
#define NUM_CYCLES 3
#define BASE_COUPLING 0.1f

// ---------------- helpers ----------------
__device__ __forceinline__ float geluf(float x) {
    // exact erf formulation (matches jax.nn.gelu(approximate=False))
    return 0.5f * x * (1.0f + erff(x * 0.70710678118654752440f));
}
__device__ __forceinline__ float sigmf_(float x) {
    return 1.0f / (1.0f + expf(-x));
}
__device__ __forceinline__ float toF(float v) { return v; }
__device__ __forceinline__ float toF(__hip_bfloat16 v) { return __bfloat162float(v); }

// ---------------- copy x -> out ----------------
__global__ __launch_bounds__(256) void copy_x_kernel(const float* __restrict__ x,
                                                     float* __restrict__ out, int n4) {
    int stride = gridDim.x * blockDim.x;
    for (int i = blockIdx.x * blockDim.x + threadIdx.x; i < n4; i += stride) {
        reinterpret_cast<float4*>(out)[i] = reinterpret_cast<const float4*>(x)[i];
    }
}

// ---------------- mean over S (two-stage, deterministic) ----------------
__global__ __launch_bounds__(256) void mean_stage1(const float* __restrict__ x,
                                                   float* __restrict__ part) {
    int b = blockIdx.x >> 5, sc = blockIdx.x & 31;
    int t = threadIdx.x;
    float acc[4] = {0.f, 0.f, 0.f, 0.f};
    const float* xb = x + ((size_t)b * PS + (size_t)sc * 128) * PD;
    for (int s = 0; s < 128; ++s) {
#pragma unroll
        for (int i = 0; i < 4; ++i) acc[i] += xb[(size_t)s * PD + t + i * 256];
    }
    float* pb = part + ((size_t)b * 32 + sc) * PD;
#pragma unroll
    for (int i = 0; i < 4; ++i) pb[t + i * 256] = acc[i];
}

__global__ __launch_bounds__(256) void mean_stage2(const float* __restrict__ part,
                                                   float* __restrict__ gc) {
    int b = blockIdx.x, t = threadIdx.x;
#pragma unroll
    for (int i = 0; i < 4; ++i) {
        int d = t + i * 256;
        float s = 0.f;
        for (int c = 0; c < 32; ++c) s += part[((size_t)b * 32 + c) * PD + d];
        gc[b * PD + d] = s * (1.0f / 4096.0f);
    }
}

// ---------------- global context net (4 rows, one block per b) ----------------
__global__ __launch_bounds__(256) void global_net_kernel(
    const float* __restrict__ gc,
    const float* __restrict__ w1, const float* __restrict__ b1,
    const float* __restrict__ w2, const float* __restrict__ b2,
    const float* __restrict__ w3, const float* __restrict__ b3,
    float* __restrict__ gf) {
    __shared__ float hb[1024];
    __shared__ float g1[512];
    __shared__ float g2[256];
    __shared__ float red[256];
    int b = blockIdx.x, t = threadIdx.x;
#pragma unroll
    for (int i = 0; i < 4; ++i) hb[t + i * 256] = gc[b * PD + t + i * 256];
    __syncthreads();
    // layer 1: 1024 -> 512, gelu
    for (int jj = t; jj < 512; jj += 256) {
        float a = b1[jj];
        for (int d = 0; d < 1024; ++d) a += hb[d] * w1[(size_t)d * 512 + jj];
        g1[jj] = geluf(a);
    }
    __syncthreads();
    // layer 2: 512 -> 256, gelu
    {
        float a = b2[t];
        for (int k = 0; k < 512; ++k) a += g1[k] * w2[(size_t)k * 256 + t];
        g2[t] = geluf(a);
    }
    __syncthreads();
    // layer 3: 256 -> 1, sigmoid
    red[t] = g2[t] * w3[t];
    __syncthreads();
    for (int s = 128; s > 0; s >>= 1) {
        if (t < s) red[t] += red[t + s];
        __syncthreads();
    }
    if (t == 0) gf[b] = sigmf_(red[0] + b3[0]);
}

// ---------------- GEMM + bias + GELU (C bf16), A fp32 or bf16 ----------------
// C[m][n] = gelu(sum_k A[m][k] * W[k][n] + bias[n])
// tile 128x128, BK=8, 256 threads, 8x8 micro-tile
template <typename AT>
__global__ __launch_bounds__(256) void gemm_bias_gelu(
    const AT* __restrict__ A, int K,
    const float* __restrict__ W, int N,
    const float* __restrict__ bias,
    __hip_bfloat16* __restrict__ C) {
    __shared__ __align__(16) float As[8][132];
    __shared__ __align__(16) float Ws[8][132];
    const int tid = threadIdx.x;
    const int m0 = blockIdx.x * 128;
    const int n0 = blockIdx.y * 128;
    const int tx = tid & 15, ty = tid >> 4;

    float acc[8][8];
#pragma unroll
    for (int i = 0; i < 8; ++i)
#pragma unroll
        for (int j = 0; j < 8; ++j) acc[i][j] = 0.f;

    const int ka = tid & 7, ra = tid >> 3;     // A loader coords
    const int jw = tid & 127, kw0 = tid >> 7;  // W loader coords

    for (int k0 = 0; k0 < K; k0 += 8) {
#pragma unroll
        for (int i = 0; i < 4; ++i) {
            int r = ra + i * 32;
            As[ka][r] = toF(A[(size_t)(m0 + r) * K + k0 + ka]);
        }
#pragma unroll
        for (int i = 0; i < 4; ++i) {
            int kk = kw0 + i * 2;
            Ws[kk][jw] = W[(size_t)(k0 + kk) * N + n0 + jw];
        }
        __syncthreads();
#pragma unroll
        for (int kk = 0; kk < 8; ++kk) {
            float a[8], w[8];
            *reinterpret_cast<float4*>(&a[0]) = *reinterpret_cast<const float4*>(&As[kk][ty * 8]);
            *reinterpret_cast<float4*>(&a[4]) = *reinterpret_cast<const float4*>(&As[kk][ty * 8 + 4]);
            *reinterpret_cast<float4*>(&w[0]) = *reinterpret_cast<const float4*>(&Ws[kk][tx * 8]);
            *reinterpret_cast<float4*>(&w[4]) = *reinterpret_cast<const float4*>(&Ws[kk][tx * 8 + 4]);
#pragma unroll
            for (int i = 0; i < 8; ++i)
#pragma unroll
                for (int j = 0; j < 8; ++j) acc[i][j] += a[i] * w[j];
        }
        __syncthreads();
    }
    // epilogue: bias + gelu + bf16 store
#pragma unroll
    for (int i = 0; i < 8; ++i) {
        int m = m0 + ty * 8 + i;
#pragma unroll
        for (int j = 0; j < 8; ++j) {
            int n = n0 + tx * 8 + j;
            float v = acc[i][j] + bias[n];
            C[(size_t)m * N + n] = __float2bfloat16(geluf(v));
        }
    }
}

// ---------------- final layer (256->1) + sigmoid + coupling + twist update ----------------
__global__ __launch_bounds__(256) void tf_update_kernel(
    const __hip_bfloat16* __restrict__ h3,  // ROWS x 256
    const float* __restrict__ w4, const float* __restrict__ b4,
    const float* __restrict__ gf, const float* __restrict__ arp,
    float* __restrict__ out) {
    const int wid = threadIdx.x >> 6, lane = threadIdx.x & 63;
    const int r = blockIdx.x * 4 + wid;
    const int b = r >> 12;  // S = 4096 rows per batch
    const __hip_bfloat16* hr = h3 + (size_t)r * 256;
    float p = 0.f;
#pragma unroll
    for (int i = 0; i < 4; ++i) {
        int k = lane + i * 64;
        p += __bfloat162float(hr[k]) * w4[k];
    }
#pragma unroll
    for (int off = 32; off; off >>= 1) p += __shfl_xor(p, off);
    float tf = sigmf_(p + b4[0]);
    float comb = 0.7f * gf[b] + 0.3f * tf;
    float c = BASE_COUPLING + arp[0] * (comb - 0.5f) * 2.0f;

    float* row = out + (size_t)r * PD;
#pragma unroll
    for (int i = 0; i < 4; ++i) {
        int d = lane + i * 64;
        float o_r = row[d];
        float o_i = row[256 + d];
        float p_r = row[512 + d];
        float p_i = row[768 + d];
        row[d]       = o_r + c * p_r;
        row[256 + d] = o_i - c * p_i;
        row[512 + d] = p_r - c * o_r;
        row[768 + d] = p_i + c * o_i;
    }
}

// ---------------- launch ----------------
extern "C" void kernel_launch(void* const* d_in, const int* in_sizes, int n_in,
                              void* d_out, int out_size, void* d_ws, size_t ws_size,
                              hipStream_t stream) {
    const float* x     = (const float*)d_in[0];
    const float* cn_w1 = (const float*)d_in[1];
    const float* cn_b1 = (const float*)d_in[2];
    const float* cn_w2 = (const float*)d_in[3];
    const float* cn_b2 = (const float*)d_in[4];
    const float* cn_w3 = (const float*)d_in[5];
    const float* cn_b3 = (const float*)d_in[6];
    const float* cn_w4 = (const float*)d_in[7];
    const float* cn_b4 = (const float*)d_in[8];
    const float* gc_w1 = (const float*)d_in[9];
    const float* gc_b1 = (const float*)d_in[10];
    const float* gc_w2 = (const float*)d_in[11];
    const float* gc_b2 = (const float*)d_in[12];
    const float* gc_w3 = (const float*)d_in[13];
    const float* gc_b3 = (const float*)d_in[14];
    const float* ar    = (const float*)d_in[15];

    float* out = (float*)d_out;

    // workspace layout (bytes)
    char* ws = (char*)d_ws;
    __hip_bfloat16* h1 = (__hip_bfloat16*)(ws);                     // ROWS*1024 bf16 = 32 MB
    __hip_bfloat16* h2 = (__hip_bfloat16*)(ws + 33554432);          // ROWS*512  bf16 = 16 MB
    __hip_bfloat16* h3 = (__hip_bfloat16*)(ws + 50331648);          // ROWS*256  bf16 =  8 MB
    float* gcpart      = (float*)(ws + 58720256);                   // B*32*1024 f32
    float* gc          = gcpart + PB * 32 * PD;                     // B*1024 f32
    float* gf          = gc + PB * PD;                              // B f32

    // out = x
    copy_x_kernel<<<2048, 256, 0, stream>>>(x, out, ROWS * PD / 4);
    // global context mean + global net (once)
    mean_stage1<<<PB * 32, 256, 0, stream>>>(x, gcpart);
    mean_stage2<<<PB, 256, 0, stream>>>(gcpart, gc);
    global_net_kernel<<<PB, 256, 0, stream>>>(gc, gc_w1, gc_b1, gc_w2, gc_b2, gc_w3, gc_b3, gf);

    for (int cyc = 0; cyc < NUM_CYCLES; ++cyc) {
        gemm_bias_gelu<float><<<dim3(ROWS / 128, 1024 / 128), 256, 0, stream>>>(
            out, 1024, cn_w1, 1024, cn_b1, h1);
        gemm_bias_gelu<__hip_bfloat16><<<dim3(ROWS / 128, 512 / 128), 256, 0, stream>>>(
            h1, 1024, cn_w2, 512, cn_b2, h2);
        gemm_bias_gelu<__hip_bfloat16><<<dim3(ROWS / 128, 256 / 128), 256, 0, stream>>>(
            h2, 512, cn_w3, 256, cn_b3, h3);
        tf_update_kernel<<<ROWS / 4, 256, 0, stream>>>(h3, cn_w4, cn_b4, gf, ar, out);
    }
}

// Round 3
// 545.219 us; speedup vs baseline: 4.4053x; 4.4053x over previous
//
#include <hip/hip_runtime.h>
#include <hip/hip_bf16.h>

// Problem constants (AdaptiveMobiusLayer): B=4, S=4096, DIM=1024
#define PB 4
#define PS 4096
#define PD 1024
#define ROWS (PB * PS)          // 16384
#define NUM_CYCLES 3
#define BASE_COUPLING 0.1f

typedef __attribute__((ext_vector_type(8))) short bf16x8;
typedef __attribute__((ext_vector_type(4))) float f32x4;

// ---------------- helpers ----------------
__device__ __forceinline__ float geluf(float x) {
    return 0.5f * x * (1.0f + erff(x * 0.70710678118654752440f));
}
__device__ __forceinline__ float sigmf_(float x) {
    return 1.0f / (1.0f + expf(-x));
}

// global_load_lds: 16B per lane, LDS dest = wave-uniform base + lane*16
#define GLD_LDS16(gsrc, ldst)                                                        \
    __builtin_amdgcn_global_load_lds(                                                \
        (const __attribute__((address_space(1))) void*)(gsrc),                       \
        (__attribute__((address_space(3))) void*)(ldst), 16, 0, 0)

// ---------------- copy x -> out (f32) + outb (bf16) ----------------
__global__ __launch_bounds__(256) void copy_cvt_kernel(const float* __restrict__ x,
                                                       float* __restrict__ out,
                                                       __hip_bfloat16* __restrict__ xb,
                                                       int n4) {
    int stride = gridDim.x * blockDim.x;
    for (int i = blockIdx.x * blockDim.x + threadIdx.x; i < n4; i += stride) {
        float4 v = reinterpret_cast<const float4*>(x)[i];
        reinterpret_cast<float4*>(out)[i] = v;
        __hip_bfloat16 h4[4] = {__float2bfloat16(v.x), __float2bfloat16(v.y),
                                __float2bfloat16(v.z), __float2bfloat16(v.w)};
        reinterpret_cast<uint2*>(xb)[i] = *reinterpret_cast<uint2*>(h4);
    }
}

// ---------------- weight transpose+convert: W[K][N] f32 -> Wt[N][K] bf16 ----------------
__global__ __launch_bounds__(256) void transpose_w_kernel(const float* __restrict__ W,
                                                          __hip_bfloat16* __restrict__ Wt,
                                                          int K, int N) {
    __shared__ float t[32][33];
    int k0 = blockIdx.x * 32, n0 = blockIdx.y * 32;
    int tx = threadIdx.x & 31, ty = threadIdx.x >> 5;  // ty 0..7
#pragma unroll
    for (int i = 0; i < 32; i += 8)
        t[ty + i][tx] = W[(size_t)(k0 + ty + i) * N + n0 + tx];
    __syncthreads();
#pragma unroll
    for (int i = 0; i < 32; i += 8)
        Wt[(size_t)(n0 + ty + i) * K + k0 + tx] = __float2bfloat16(t[tx][ty + i]);
}

// ---------------- mean over S (two-stage, deterministic) ----------------
__global__ __launch_bounds__(256) void mean_stage1(const float* __restrict__ x,
                                                   float* __restrict__ part) {
    int b = blockIdx.x >> 5, sc = blockIdx.x & 31;
    int t = threadIdx.x;
    float acc[4] = {0.f, 0.f, 0.f, 0.f};
    const float* xb = x + ((size_t)b * PS + (size_t)sc * 128) * PD;
    for (int s = 0; s < 128; ++s) {
#pragma unroll
        for (int i = 0; i < 4; ++i) acc[i] += xb[(size_t)s * PD + t + i * 256];
    }
    float* pb = part + ((size_t)b * 32 + sc) * PD;
#pragma unroll
    for (int i = 0; i < 4; ++i) pb[t + i * 256] = acc[i];
}

__global__ __launch_bounds__(256) void mean_stage2(const float* __restrict__ part,
                                                   float* __restrict__ gc) {
    int b = blockIdx.x, t = threadIdx.x;
#pragma unroll
    for (int i = 0; i < 4; ++i) {
        int d = t + i * 256;
        float s = 0.f;
        for (int c = 0; c < 32; ++c) s += part[((size_t)b * 32 + c) * PD + d];
        gc[b * PD + d] = s * (1.0f / 4096.0f);
    }
}

// ---------------- global context net (4 rows, one block per b) ----------------
__global__ __launch_bounds__(256) void global_net_kernel(
    const float* __restrict__ gc,
    const float* __restrict__ w1, const float* __restrict__ b1,
    const float* __restrict__ w2, const float* __restrict__ b2,
    const float* __restrict__ w3, const float* __restrict__ b3,
    float* __restrict__ gf) {
    __shared__ float hb[1024];
    __shared__ float g1[512];
    __shared__ float g2[256];
    __shared__ float red[256];
    int b = blockIdx.x, t = threadIdx.x;
#pragma unroll
    for (int i = 0; i < 4; ++i) hb[t + i * 256] = gc[b * PD + t + i * 256];
    __syncthreads();
    for (int jj = t; jj < 512; jj += 256) {
        float a = b1[jj];
        for (int d = 0; d < 1024; ++d) a += hb[d] * w1[(size_t)d * 512 + jj];
        g1[jj] = geluf(a);
    }
    __syncthreads();
    {
        float a = b2[t];
        for (int k = 0; k < 512; ++k) a += g1[k] * w2[(size_t)k * 256 + t];
        g2[t] = geluf(a);
    }
    __syncthreads();
    red[t] = g2[t] * w3[t];
    __syncthreads();
    for (int s = 128; s > 0; s >>= 1) {
        if (t < s) red[t] += red[t + s];
        __syncthreads();
    }
    if (t == 0) gf[b] = sigmf_(red[0] + b3[0]);
}

// ---------------- MFMA GEMM + bias + GELU ----------------
// C[m][n] = gelu(sum_k A[m][k] * Wt[n][k] + bias[n]),  A: MxK bf16, Wt: NxK bf16
// 128x128 tile, BK=32, 256 threads = 4 waves (2x2), each wave 64x64 (4x4 16x16 frags)
__global__ __launch_bounds__(256) void gemm_mfma_kernel(
    const __hip_bfloat16* __restrict__ A,
    const __hip_bfloat16* __restrict__ Wt,
    const float* __restrict__ bias,
    __hip_bfloat16* __restrict__ C,
    int K, int N) {
    __shared__ __align__(16) __hip_bfloat16 Als[128 * 32];
    __shared__ __align__(16) __hip_bfloat16 Bls[128 * 32];
    const int tid = threadIdx.x;
    const int wave = tid >> 6, lane = tid & 63;
    const int m0 = blockIdx.x * 128, n0 = blockIdx.y * 128;
    const int wr = wave >> 1, wc = wave & 1;
    const int fr = lane & 15, fq = lane >> 4;

    f32x4 acc[4][4] = {};

    // stage one BK=32 K-slice of A and B tiles into LDS (linear [128][32] layout)
    auto stage = [&](int kt) {
#pragma unroll
        for (int j = 0; j < 2; ++j) {
            int o = wave * 2048 + j * 1024;     // wave-uniform LDS byte base
            int chunk = (o >> 4) + lane;        // 16B chunk index, per-lane
            int mm = chunk >> 2;
            int ks = (chunk & 3) * 8;
            GLD_LDS16(A + (size_t)(m0 + mm) * K + kt + ks, (char*)Als + o);
            GLD_LDS16(Wt + (size_t)(n0 + mm) * K + kt + ks, (char*)Bls + o);
        }
    };

    stage(0);
    for (int kt = 0; kt < K; kt += 32) {
        __syncthreads();  // staging visible (compiler drains vmcnt before barrier)
        bf16x8 av[4], bv[4];
#pragma unroll
        for (int mi = 0; mi < 4; ++mi)
            av[mi] = *reinterpret_cast<const bf16x8*>(Als + (wr * 64 + mi * 16 + fr) * 32 + fq * 8);
#pragma unroll
        for (int ni = 0; ni < 4; ++ni)
            bv[ni] = *reinterpret_cast<const bf16x8*>(Bls + (wc * 64 + ni * 16 + fr) * 32 + fq * 8);
#pragma unroll
        for (int mi = 0; mi < 4; ++mi)
#pragma unroll
            for (int ni = 0; ni < 4; ++ni)
                acc[mi][ni] = __builtin_amdgcn_mfma_f32_16x16x32_bf16(av[mi], bv[ni], acc[mi][ni], 0, 0, 0);
        if (kt + 32 < K) {
            __syncthreads();  // all reads done before overwrite
            stage(kt + 32);
        }
    }

    // epilogue: C/D layout col=lane&15, row=(lane>>4)*4+reg  [m89-verified]
#pragma unroll
    for (int mi = 0; mi < 4; ++mi) {
#pragma unroll
        for (int ni = 0; ni < 4; ++ni) {
            int n = n0 + wc * 64 + ni * 16 + fr;
            float bs = bias[n];
#pragma unroll
            for (int r = 0; r < 4; ++r) {
                int m = m0 + wr * 64 + mi * 16 + fq * 4 + r;
                float v = acc[mi][ni][r] + bs;
                C[(size_t)m * N + n] = __float2bfloat16(geluf(v));
            }
        }
    }
}

// ---------------- final layer (256->1) + sigmoid + coupling + twist update ----------------
__global__ __launch_bounds__(256) void tf_update_kernel(
    const __hip_bfloat16* __restrict__ h3,  // ROWS x 256
    const float* __restrict__ w4, const float* __restrict__ b4,
    const float* __restrict__ gf, const float* __restrict__ arp,
    float* __restrict__ out, __hip_bfloat16* __restrict__ outb) {
    const int wid = threadIdx.x >> 6, lane = threadIdx.x & 63;
    const int r = blockIdx.x * 4 + wid;
    const int b = r >> 12;  // S = 4096 rows per batch
    const __hip_bfloat16* hr = h3 + (size_t)r * 256;
    float p = 0.f;
#pragma unroll
    for (int i = 0; i < 4; ++i) {
        int k = lane + i * 64;
        p += __bfloat162float(hr[k]) * w4[k];
    }
#pragma unroll
    for (int off = 32; off; off >>= 1) p += __shfl_xor(p, off);
    float tf = sigmf_(p + b4[0]);
    float comb = 0.7f * gf[b] + 0.3f * tf;
    float c = BASE_COUPLING + arp[0] * (comb - 0.5f) * 2.0f;

    float* row = out + (size_t)r * PD;
    __hip_bfloat16* rowb = outb + (size_t)r * PD;
#pragma unroll
    for (int i = 0; i < 4; ++i) {
        int d = lane + i * 64;
        float o_r = row[d];
        float o_i = row[256 + d];
        float p_r = row[512 + d];
        float p_i = row[768 + d];
        float n0 = o_r + c * p_r;
        float n1 = o_i - c * p_i;
        float n2 = p_r - c * o_r;
        float n3 = p_i + c * o_i;
        row[d] = n0;       rowb[d] = __float2bfloat16(n0);
        row[256 + d] = n1; rowb[256 + d] = __float2bfloat16(n1);
        row[512 + d] = n2; rowb[512 + d] = __float2bfloat16(n2);
        row[768 + d] = n3; rowb[768 + d] = __float2bfloat16(n3);
    }
}

// ---------------- launch ----------------
extern "C" void kernel_launch(void* const* d_in, const int* in_sizes, int n_in,
                              void* d_out, int out_size, void* d_ws, size_t ws_size,
                              hipStream_t stream) {
    const float* x     = (const float*)d_in[0];
    const float* cn_w1 = (const float*)d_in[1];
    const float* cn_b1 = (const float*)d_in[2];
    const float* cn_w2 = (const float*)d_in[3];
    const float* cn_b2 = (const float*)d_in[4];
    const float* cn_w3 = (const float*)d_in[5];
    const float* cn_b3 = (const float*)d_in[6];
    const float* cn_w4 = (const float*)d_in[7];
    const float* cn_b4 = (const float*)d_in[8];
    const float* gc_w1 = (const float*)d_in[9];
    const float* gc_b1 = (const float*)d_in[10];
    const float* gc_w2 = (const float*)d_in[11];
    const float* gc_b2 = (const float*)d_in[12];
    const float* gc_w3 = (const float*)d_in[13];
    const float* gc_b3 = (const float*)d_in[14];
    const float* ar    = (const float*)d_in[15];

    float* out = (float*)d_out;

    // workspace layout (bytes); total ~93 MB
    char* ws = (char*)d_ws;
    __hip_bfloat16* h1   = (__hip_bfloat16*)(ws);                      // 16384*1024*2 = 32 MB
    __hip_bfloat16* h2   = (__hip_bfloat16*)(ws + ((size_t)32 << 20)); // 16 MB
    __hip_bfloat16* h3   = (__hip_bfloat16*)(ws + ((size_t)48 << 20)); // 8 MB
    __hip_bfloat16* outb = (__hip_bfloat16*)(ws + ((size_t)56 << 20)); // 32 MB
    __hip_bfloat16* wt1  = (__hip_bfloat16*)(ws + ((size_t)88 << 20)); // 2 MB
    __hip_bfloat16* wt2  = (__hip_bfloat16*)(ws + ((size_t)90 << 20)); // 1 MB
    __hip_bfloat16* wt3  = (__hip_bfloat16*)(ws + ((size_t)91 << 20)); // 0.25 MB
    float* gcpart        = (float*)(ws + ((size_t)92 << 20));          // B*32*1024 f32
    float* gc            = gcpart + PB * 32 * PD;                      // B*1024
    float* gf            = gc + PB * PD;                               // B

    // weights: fp32 [K][N] -> bf16 [N][K]
    transpose_w_kernel<<<dim3(32, 32), 256, 0, stream>>>(cn_w1, wt1, 1024, 1024);
    transpose_w_kernel<<<dim3(32, 16), 256, 0, stream>>>(cn_w2, wt2, 1024, 512);
    transpose_w_kernel<<<dim3(16, 8), 256, 0, stream>>>(cn_w3, wt3, 512, 256);

    // out = x (f32) and outb = bf16(x)
    copy_cvt_kernel<<<2048, 256, 0, stream>>>(x, out, outb, ROWS * PD / 4);

    // global context mean + global net (once)
    mean_stage1<<<PB * 32, 256, 0, stream>>>(x, gcpart);
    mean_stage2<<<PB, 256, 0, stream>>>(gcpart, gc);
    global_net_kernel<<<PB, 256, 0, stream>>>(gc, gc_w1, gc_b1, gc_w2, gc_b2, gc_w3, gc_b3, gf);

    for (int cyc = 0; cyc < NUM_CYCLES; ++cyc) {
        gemm_mfma_kernel<<<dim3(ROWS / 128, 1024 / 128), 256, 0, stream>>>(
            outb, wt1, cn_b1, h1, 1024, 1024);
        gemm_mfma_kernel<<<dim3(ROWS / 128, 512 / 128), 256, 0, stream>>>(
            h1, wt2, cn_b2, h2, 1024, 512);
        gemm_mfma_kernel<<<dim3(ROWS / 128, 256 / 128), 256, 0, stream>>>(
            h2, wt3, cn_b3, h3, 512, 256);
        tf_update_kernel<<<ROWS / 4, 256, 0, stream>>>(h3, cn_w4, cn_b4, gf, ar, out, outb);
    }
}

// Round 4
// 484.574 us; speedup vs baseline: 4.9566x; 1.1252x over previous
//
#include <hip/hip_runtime.h>
#include <hip/hip_bf16.h>

// Problem constants (AdaptiveMobiusLayer): B=4, S=4096, DIM=1024
#define PB 4
#define PS 4096
#define PD 1024
#define ROWS (PB * PS)          // 16384
#define NUM_CYCLES 3
#define BASE_COUPLING 0.1f

typedef __attribute__((ext_vector_type(8))) short bf16x8;
typedef __attribute__((ext_vector_type(4))) float f32x4;

// ---------------- helpers ----------------
__device__ __forceinline__ float geluf(float x) {
    return 0.5f * x * (1.0f + erff(x * 0.70710678118654752440f));
}
__device__ __forceinline__ float sigmf_(float x) {
    return 1.0f / (1.0f + expf(-x));
}
__device__ __forceinline__ uint2 pk4(float4 v) {
    __hip_bfloat16 h[4] = {__float2bfloat16(v.x), __float2bfloat16(v.y),
                           __float2bfloat16(v.z), __float2bfloat16(v.w)};
    return *reinterpret_cast<uint2*>(h);
}
__device__ __forceinline__ float4 axpy4(float4 a, float s, float4 b) {
    // a + s*b componentwise
    return make_float4(fmaf(s, b.x, a.x), fmaf(s, b.y, a.y),
                       fmaf(s, b.z, a.z), fmaf(s, b.w, a.w));
}

// global_load_lds: 16B per lane, LDS dest = wave-uniform base + lane*16
#define GLD_LDS16(gsrc, ldst)                                                        \
    __builtin_amdgcn_global_load_lds(                                                \
        (const __attribute__((address_space(1))) void*)(gsrc),                       \
        (__attribute__((address_space(3))) void*)(ldst), 16, 0, 0)

// ---------------- fused: out=x (f32), outb=bf16(x), partial mean over S ----------------
// grid: 256 blocks = b(4) x sc(64); each block: 64 rows of 1024
__global__ __launch_bounds__(256) void copy_mean_kernel(const float* __restrict__ x,
                                                        float* __restrict__ out,
                                                        __hip_bfloat16* __restrict__ outb,
                                                        float* __restrict__ part) {
    int b = blockIdx.x >> 6, sc = blockIdx.x & 63;
    size_t base = ((size_t)b * PS + (size_t)sc * 64) * PD;
    const float4* x4 = reinterpret_cast<const float4*>(x + base);
    float4* o4 = reinterpret_cast<float4*>(out + base);
    uint2* ob = reinterpret_cast<uint2*>(outb + base);
    int t = threadIdx.x;
    float4 acc = make_float4(0.f, 0.f, 0.f, 0.f);
    for (int r = 0; r < 64; ++r) {
        float4 v = x4[r * 256 + t];
        o4[r * 256 + t] = v;
        ob[r * 256 + t] = pk4(v);
        acc.x += v.x; acc.y += v.y; acc.z += v.z; acc.w += v.w;
    }
    reinterpret_cast<float4*>(part + ((size_t)(b * 64 + sc)) * PD)[t] = acc;
}

__global__ __launch_bounds__(256) void mean_stage2(const float* __restrict__ part,
                                                   float* __restrict__ gc) {
    int b = blockIdx.x, t = threadIdx.x;
    float4 s = make_float4(0.f, 0.f, 0.f, 0.f);
    for (int c = 0; c < 64; ++c) {
        float4 v = reinterpret_cast<const float4*>(part + ((size_t)(b * 64 + c)) * PD)[t];
        s.x += v.x; s.y += v.y; s.z += v.z; s.w += v.w;
    }
    s.x *= (1.0f / 4096.0f); s.y *= (1.0f / 4096.0f);
    s.z *= (1.0f / 4096.0f); s.w *= (1.0f / 4096.0f);
    reinterpret_cast<float4*>(gc + (size_t)b * PD)[t] = s;
}

// ---------------- weight transpose+convert: W[K][N] f32 -> Wt[N][K] bf16 ----------------
__global__ __launch_bounds__(256) void transpose_w_kernel(const float* __restrict__ W,
                                                          __hip_bfloat16* __restrict__ Wt,
                                                          int K, int N) {
    __shared__ float t[32][33];
    int k0 = blockIdx.x * 32, n0 = blockIdx.y * 32;
    int tx = threadIdx.x & 31, ty = threadIdx.x >> 5;  // ty 0..7
#pragma unroll
    for (int i = 0; i < 32; i += 8)
        t[ty + i][tx] = W[(size_t)(k0 + ty + i) * N + n0 + tx];
    __syncthreads();
#pragma unroll
    for (int i = 0; i < 32; i += 8)
        Wt[(size_t)(n0 + ty + i) * K + k0 + tx] = __float2bfloat16(t[tx][ty + i]);
}

// ---------------- global context net, parallelized ----------------
// gn1: 1024 -> 512, gelu. grid (4, 8): block = (b, 64 outputs). wave = k-chunk of 256.
__global__ __launch_bounds__(256) void gn1_kernel(const float* __restrict__ gc,
                                                  const float* __restrict__ w1,
                                                  const float* __restrict__ b1,
                                                  float* __restrict__ g1) {
    __shared__ float gcs[1024];
    __shared__ float red[4][64];
    int b = blockIdx.x, j0 = blockIdx.y * 64;
    int t = threadIdx.x, wave = t >> 6, lane = t & 63;
    for (int i = t; i < 1024; i += 256) gcs[i] = gc[(size_t)b * PD + i];
    __syncthreads();
    int j = j0 + lane;
    float a = 0.f;
    int k0 = wave * 256;
    for (int k = k0; k < k0 + 256; ++k) a += gcs[k] * w1[(size_t)k * 512 + j];
    red[wave][lane] = a;
    __syncthreads();
    if (wave == 0) {
        float v = red[0][lane] + red[1][lane] + red[2][lane] + red[3][lane] + b1[j];
        g1[(size_t)b * 512 + j] = geluf(v);
    }
}

// gn2: 512 -> 256, gelu. grid (4, 4): block = (b, 64 outputs). wave = k-chunk of 128.
__global__ __launch_bounds__(256) void gn2_kernel(const float* __restrict__ g1,
                                                  const float* __restrict__ w2,
                                                  const float* __restrict__ b2,
                                                  float* __restrict__ g2) {
    __shared__ float g1s[512];
    __shared__ float red[4][64];
    int b = blockIdx.x, j0 = blockIdx.y * 64;
    int t = threadIdx.x, wave = t >> 6, lane = t & 63;
    for (int i = t; i < 512; i += 256) g1s[i] = g1[(size_t)b * 512 + i];
    __syncthreads();
    int j = j0 + lane;
    float a = 0.f;
    int k0 = wave * 128;
    for (int k = k0; k < k0 + 128; ++k) a += g1s[k] * w2[(size_t)k * 256 + j];
    red[wave][lane] = a;
    __syncthreads();
    if (wave == 0) {
        float v = red[0][lane] + red[1][lane] + red[2][lane] + red[3][lane] + b2[j];
        g2[(size_t)b * 256 + j] = geluf(v);
    }
}

// gn3: 256 -> 1, sigmoid. grid 4 blocks.
__global__ __launch_bounds__(256) void gn3_kernel(const float* __restrict__ g2,
                                                  const float* __restrict__ w3,
                                                  const float* __restrict__ b3,
                                                  float* __restrict__ gf) {
    __shared__ float red[256];
    int b = blockIdx.x, t = threadIdx.x;
    red[t] = g2[(size_t)b * 256 + t] * w3[t];
    __syncthreads();
    for (int s = 128; s > 0; s >>= 1) {
        if (t < s) red[t] += red[t + s];
        __syncthreads();
    }
    if (t == 0) gf[b] = sigmf_(red[0] + b3[0]);
}

// ---------------- MFMA GEMM + bias + GELU ----------------
// C[m][n] = gelu(sum_k A[m][k] * Wt[n][k] + bias[n]),  A: MxK bf16, Wt: NxK bf16
// 128x128 tile, BK=32, 256 threads = 4 waves (2x2), each wave 64x64 (4x4 16x16 frags)
__global__ __launch_bounds__(256) void gemm_mfma_kernel(
    const __hip_bfloat16* __restrict__ A,
    const __hip_bfloat16* __restrict__ Wt,
    const float* __restrict__ bias,
    __hip_bfloat16* __restrict__ C,
    int K, int N) {
    __shared__ __align__(16) __hip_bfloat16 Als[128 * 32];
    __shared__ __align__(16) __hip_bfloat16 Bls[128 * 32];
    const int tid = threadIdx.x;
    const int wave = tid >> 6, lane = tid & 63;
    const int m0 = blockIdx.x * 128, n0 = blockIdx.y * 128;
    const int wr = wave >> 1, wc = wave & 1;
    const int fr = lane & 15, fq = lane >> 4;

    f32x4 acc[4][4] = {};

    auto stage = [&](int kt) {
#pragma unroll
        for (int j = 0; j < 2; ++j) {
            int o = wave * 2048 + j * 1024;     // wave-uniform LDS byte base
            int chunk = (o >> 4) + lane;        // 16B chunk index, per-lane
            int mm = chunk >> 2;
            int ks = (chunk & 3) * 8;
            GLD_LDS16(A + (size_t)(m0 + mm) * K + kt + ks, (char*)Als + o);
            GLD_LDS16(Wt + (size_t)(n0 + mm) * K + kt + ks, (char*)Bls + o);
        }
    };

    stage(0);
    for (int kt = 0; kt < K; kt += 32) {
        __syncthreads();
        bf16x8 av[4], bv[4];
#pragma unroll
        for (int mi = 0; mi < 4; ++mi)
            av[mi] = *reinterpret_cast<const bf16x8*>(Als + (wr * 64 + mi * 16 + fr) * 32 + fq * 8);
#pragma unroll
        for (int ni = 0; ni < 4; ++ni)
            bv[ni] = *reinterpret_cast<const bf16x8*>(Bls + (wc * 64 + ni * 16 + fr) * 32 + fq * 8);
#pragma unroll
        for (int mi = 0; mi < 4; ++mi)
#pragma unroll
            for (int ni = 0; ni < 4; ++ni)
                acc[mi][ni] = __builtin_amdgcn_mfma_f32_16x16x32_bf16(av[mi], bv[ni], acc[mi][ni], 0, 0, 0);
        if (kt + 32 < K) {
            __syncthreads();
            stage(kt + 32);
        }
    }

    // epilogue: C/D layout col=lane&15, row=(lane>>4)*4+reg  [m89-verified]
#pragma unroll
    for (int mi = 0; mi < 4; ++mi) {
#pragma unroll
        for (int ni = 0; ni < 4; ++ni) {
            int n = n0 + wc * 64 + ni * 16 + fr;
            float bs = bias[n];
#pragma unroll
            for (int r = 0; r < 4; ++r) {
                int m = m0 + wr * 64 + mi * 16 + fq * 4 + r;
                float v = acc[mi][ni][r] + bs;
                C[(size_t)m * N + n] = __float2bfloat16(geluf(v));
            }
        }
    }
}

// ---------------- final layer (256->1) + sigmoid + coupling + twist update ----------------
__global__ __launch_bounds__(256) void tf_update_kernel(
    const __hip_bfloat16* __restrict__ h3,  // ROWS x 256
    const float* __restrict__ w4, const float* __restrict__ b4,
    const float* __restrict__ gf, const float* __restrict__ arp,
    float* __restrict__ out, __hip_bfloat16* __restrict__ outb) {
    const int wid = threadIdx.x >> 6, lane = threadIdx.x & 63;
    const int r = blockIdx.x * 4 + wid;
    const int b = r >> 12;  // S = 4096 rows per batch

    // dot(h3_row, w4): lane covers k = lane*4 .. lane*4+3 (vector loads)
    uint2 hv = reinterpret_cast<const uint2*>(h3 + (size_t)r * 256)[lane];
    __hip_bfloat16 hh[4];
    *reinterpret_cast<uint2*>(hh) = hv;
    float4 wv = reinterpret_cast<const float4*>(w4)[lane];
    float p = __bfloat162float(hh[0]) * wv.x + __bfloat162float(hh[1]) * wv.y +
              __bfloat162float(hh[2]) * wv.z + __bfloat162float(hh[3]) * wv.w;
#pragma unroll
    for (int off = 32; off; off >>= 1) p += __shfl_xor(p, off);
    float tf = sigmf_(p + b4[0]);
    float comb = 0.7f * gf[b] + 0.3f * tf;
    float c = BASE_COUPLING + arp[0] * (comb - 0.5f) * 2.0f;

    float4* row4 = reinterpret_cast<float4*>(out + (size_t)r * PD);
    uint2* rb4 = reinterpret_cast<uint2*>(outb + (size_t)r * PD);
    float4 o_r = row4[lane];
    float4 o_i = row4[64 + lane];
    float4 p_r = row4[128 + lane];
    float4 p_i = row4[192 + lane];
    float4 n0 = axpy4(o_r, c, p_r);            // o_r + c*p_r
    float4 n1 = axpy4(o_i, -c, p_i);           // o_i - c*p_i
    float4 n2 = axpy4(p_r, -c, o_r);           // p_r - c*o_r
    float4 n3 = axpy4(p_i, c, o_i);            // p_i + c*o_i
    row4[lane] = n0;        rb4[lane] = pk4(n0);
    row4[64 + lane] = n1;   rb4[64 + lane] = pk4(n1);
    row4[128 + lane] = n2;  rb4[128 + lane] = pk4(n2);
    row4[192 + lane] = n3;  rb4[192 + lane] = pk4(n3);
}

// ---------------- launch ----------------
extern "C" void kernel_launch(void* const* d_in, const int* in_sizes, int n_in,
                              void* d_out, int out_size, void* d_ws, size_t ws_size,
                              hipStream_t stream) {
    const float* x     = (const float*)d_in[0];
    const float* cn_w1 = (const float*)d_in[1];
    const float* cn_b1 = (const float*)d_in[2];
    const float* cn_w2 = (const float*)d_in[3];
    const float* cn_b2 = (const float*)d_in[4];
    const float* cn_w3 = (const float*)d_in[5];
    const float* cn_b3 = (const float*)d_in[6];
    const float* cn_w4 = (const float*)d_in[7];
    const float* cn_b4 = (const float*)d_in[8];
    const float* gc_w1 = (const float*)d_in[9];
    const float* gc_b1 = (const float*)d_in[10];
    const float* gc_w2 = (const float*)d_in[11];
    const float* gc_b2 = (const float*)d_in[12];
    const float* gc_w3 = (const float*)d_in[13];
    const float* gc_b3 = (const float*)d_in[14];
    const float* ar    = (const float*)d_in[15];

    float* out = (float*)d_out;

    // workspace layout (bytes); ~92.3 MB total
    char* ws = (char*)d_ws;
    __hip_bfloat16* h1   = (__hip_bfloat16*)(ws);                      // 32 MB
    __hip_bfloat16* h2   = (__hip_bfloat16*)(ws + ((size_t)32 << 20)); // 16 MB
    __hip_bfloat16* h3   = (__hip_bfloat16*)(ws + ((size_t)48 << 20)); // 8 MB
    __hip_bfloat16* outb = (__hip_bfloat16*)(ws + ((size_t)56 << 20)); // 32 MB
    __hip_bfloat16* wt1  = (__hip_bfloat16*)(ws + ((size_t)88 << 20)); // 2 MB
    __hip_bfloat16* wt2  = (__hip_bfloat16*)(ws + ((size_t)90 << 20)); // 1 MB
    __hip_bfloat16* wt3  = (__hip_bfloat16*)(ws + ((size_t)91 << 20)); // 0.25 MB
    float* part          = (float*)(ws + ((size_t)91 << 20) + (1 << 18)); // 1 MB: 4*64*1024 f32
    float* gc            = part + 4 * 64 * PD;                         // 4*1024
    float* g1            = gc + 4 * PD;                                // 4*512
    float* g2            = g1 + 4 * 512;                               // 4*256
    float* gf            = g2 + 4 * 256;                               // 4

    // weights: fp32 [K][N] -> bf16 [N][K]
    transpose_w_kernel<<<dim3(32, 32), 256, 0, stream>>>(cn_w1, wt1, 1024, 1024);
    transpose_w_kernel<<<dim3(32, 16), 256, 0, stream>>>(cn_w2, wt2, 1024, 512);
    transpose_w_kernel<<<dim3(16, 8), 256, 0, stream>>>(cn_w3, wt3, 512, 256);

    // fused copy + cvt + partial mean, then finish mean
    copy_mean_kernel<<<256, 256, 0, stream>>>(x, out, outb, part);
    mean_stage2<<<PB, 256, 0, stream>>>(part, gc);

    // global net, parallelized
    gn1_kernel<<<dim3(PB, 8), 256, 0, stream>>>(gc, gc_w1, gc_b1, g1);
    gn2_kernel<<<dim3(PB, 4), 256, 0, stream>>>(g1, gc_w2, gc_b2, g2);
    gn3_kernel<<<PB, 256, 0, stream>>>(g2, gc_w3, gc_b3, gf);

    for (int cyc = 0; cyc < NUM_CYCLES; ++cyc) {
        gemm_mfma_kernel<<<dim3(ROWS / 128, 1024 / 128), 256, 0, stream>>>(
            outb, wt1, cn_b1, h1, 1024, 1024);
        gemm_mfma_kernel<<<dim3(ROWS / 128, 512 / 128), 256, 0, stream>>>(
            h1, wt2, cn_b2, h2, 1024, 512);
        gemm_mfma_kernel<<<dim3(ROWS / 128, 256 / 128), 256, 0, stream>>>(
            h2, wt3, cn_b3, h3, 512, 256);
        tf_update_kernel<<<ROWS / 4, 256, 0, stream>>>(h3, cn_w4, cn_b4, gf, ar, out, outb);
    }
}

// Round 5
// 483.625 us; speedup vs baseline: 4.9663x; 1.0020x over previous
//
#include <hip/hip_runtime.h>
#include <hip/hip_bf16.h>

// Problem constants (AdaptiveMobiusLayer): B=4, S=4096, DIM=1024
#define PB 4
#define PS 4096
#define PD 1024
#define ROWS (PB * PS)          // 16384
#define NUM_CYCLES 3
#define BASE_COUPLING 0.1f

typedef __attribute__((ext_vector_type(8))) short bf16x8;
typedef __attribute__((ext_vector_type(4))) float f32x4;

// ---------------- helpers ----------------
__device__ __forceinline__ float geluf(float x) {
    return 0.5f * x * (1.0f + erff(x * 0.70710678118654752440f));
}
__device__ __forceinline__ float sigmf_(float x) {
    return 1.0f / (1.0f + expf(-x));
}
__device__ __forceinline__ uint2 pk4(float4 v) {
    __hip_bfloat16 h[4] = {__float2bfloat16(v.x), __float2bfloat16(v.y),
                           __float2bfloat16(v.z), __float2bfloat16(v.w)};
    return *reinterpret_cast<uint2*>(h);
}
__device__ __forceinline__ float4 axpy4(float4 a, float s, float4 b) {
    return make_float4(fmaf(s, b.x, a.x), fmaf(s, b.y, a.y),
                       fmaf(s, b.z, a.z), fmaf(s, b.w, a.w));
}

// global_load_lds: 16B per lane, LDS dest = wave-uniform base + lane*16
#define GLD_LDS16(gsrc, ldst)                                                        \
    __builtin_amdgcn_global_load_lds(                                                \
        (const __attribute__((address_space(1))) void*)(gsrc),                       \
        (__attribute__((address_space(3))) void*)(ldst), 16, 0, 0)

#define ASM_VMCNT4() asm volatile("s_waitcnt vmcnt(4)" ::: "memory")
#define ASM_VMCNT0() asm volatile("s_waitcnt vmcnt(0)" ::: "memory")
#define ASM_LGKM0()  asm volatile("s_waitcnt lgkmcnt(0)" ::: "memory")
#define SCHED_FENCE() __builtin_amdgcn_sched_barrier(0)

// ---------------- fused: out=x (f32), outb=bf16(x), partial mean over S ----------------
__global__ __launch_bounds__(256) void copy_mean_kernel(const float* __restrict__ x,
                                                        float* __restrict__ out,
                                                        __hip_bfloat16* __restrict__ outb,
                                                        float* __restrict__ part) {
    int b = blockIdx.x >> 6, sc = blockIdx.x & 63;
    size_t base = ((size_t)b * PS + (size_t)sc * 64) * PD;
    const float4* x4 = reinterpret_cast<const float4*>(x + base);
    float4* o4 = reinterpret_cast<float4*>(out + base);
    uint2* ob = reinterpret_cast<uint2*>(outb + base);
    int t = threadIdx.x;
    float4 acc = make_float4(0.f, 0.f, 0.f, 0.f);
    for (int r = 0; r < 64; ++r) {
        float4 v = x4[r * 256 + t];
        o4[r * 256 + t] = v;
        ob[r * 256 + t] = pk4(v);
        acc.x += v.x; acc.y += v.y; acc.z += v.z; acc.w += v.w;
    }
    reinterpret_cast<float4*>(part + ((size_t)(b * 64 + sc)) * PD)[t] = acc;
}

__global__ __launch_bounds__(256) void mean_stage2(const float* __restrict__ part,
                                                   float* __restrict__ gc) {
    int b = blockIdx.x, t = threadIdx.x;
    float4 s = make_float4(0.f, 0.f, 0.f, 0.f);
    for (int c = 0; c < 64; ++c) {
        float4 v = reinterpret_cast<const float4*>(part + ((size_t)(b * 64 + c)) * PD)[t];
        s.x += v.x; s.y += v.y; s.z += v.z; s.w += v.w;
    }
    s.x *= (1.0f / 4096.0f); s.y *= (1.0f / 4096.0f);
    s.z *= (1.0f / 4096.0f); s.w *= (1.0f / 4096.0f);
    reinterpret_cast<float4*>(gc + (size_t)b * PD)[t] = s;
}

// ---------------- weight transpose+convert: W[K][N] f32 -> Wt[N][K] bf16 ----------------
__global__ __launch_bounds__(256) void transpose_w_kernel(const float* __restrict__ W,
                                                          __hip_bfloat16* __restrict__ Wt,
                                                          int K, int N) {
    __shared__ float t[32][33];
    int k0 = blockIdx.x * 32, n0 = blockIdx.y * 32;
    int tx = threadIdx.x & 31, ty = threadIdx.x >> 5;  // ty 0..7
#pragma unroll
    for (int i = 0; i < 32; i += 8)
        t[ty + i][tx] = W[(size_t)(k0 + ty + i) * N + n0 + tx];
    __syncthreads();
#pragma unroll
    for (int i = 0; i < 32; i += 8)
        Wt[(size_t)(n0 + ty + i) * K + k0 + tx] = __float2bfloat16(t[tx][ty + i]);
}

// ---------------- global context net, parallelized ----------------
__global__ __launch_bounds__(256) void gn1_kernel(const float* __restrict__ gc,
                                                  const float* __restrict__ w1,
                                                  const float* __restrict__ b1,
                                                  float* __restrict__ g1) {
    __shared__ float gcs[1024];
    __shared__ float red[4][64];
    int b = blockIdx.x, j0 = blockIdx.y * 64;
    int t = threadIdx.x, wave = t >> 6, lane = t & 63;
    for (int i = t; i < 1024; i += 256) gcs[i] = gc[(size_t)b * PD + i];
    __syncthreads();
    int j = j0 + lane;
    float a = 0.f;
    int k0 = wave * 256;
    for (int k = k0; k < k0 + 256; ++k) a += gcs[k] * w1[(size_t)k * 512 + j];
    red[wave][lane] = a;
    __syncthreads();
    if (wave == 0) {
        float v = red[0][lane] + red[1][lane] + red[2][lane] + red[3][lane] + b1[j];
        g1[(size_t)b * 512 + j] = geluf(v);
    }
}

__global__ __launch_bounds__(256) void gn2_kernel(const float* __restrict__ g1,
                                                  const float* __restrict__ w2,
                                                  const float* __restrict__ b2,
                                                  float* __restrict__ g2) {
    __shared__ float g1s[512];
    __shared__ float red[4][64];
    int b = blockIdx.x, j0 = blockIdx.y * 64;
    int t = threadIdx.x, wave = t >> 6, lane = t & 63;
    for (int i = t; i < 512; i += 256) g1s[i] = g1[(size_t)b * 512 + i];
    __syncthreads();
    int j = j0 + lane;
    float a = 0.f;
    int k0 = wave * 128;
    for (int k = k0; k < k0 + 128; ++k) a += g1s[k] * w2[(size_t)k * 256 + j];
    red[wave][lane] = a;
    __syncthreads();
    if (wave == 0) {
        float v = red[0][lane] + red[1][lane] + red[2][lane] + red[3][lane] + b2[j];
        g2[(size_t)b * 256 + j] = geluf(v);
    }
}

__global__ __launch_bounds__(256) void gn3_kernel(const float* __restrict__ g2,
                                                  const float* __restrict__ w3,
                                                  const float* __restrict__ b3,
                                                  float* __restrict__ gf) {
    __shared__ float red[256];
    int b = blockIdx.x, t = threadIdx.x;
    red[t] = g2[(size_t)b * 256 + t] * w3[t];
    __syncthreads();
    for (int s = 128; s > 0; s >>= 1) {
        if (t < s) red[t] += red[t + s];
        __syncthreads();
    }
    if (t == 0) gf[b] = sigmf_(red[0] + b3[0]);
}

// ---------------- MFMA GEMM + bias + GELU (double-buffered, counted vmcnt, swizzled LDS) ----
// C[m][n] = gelu(sum_k A[m][k] * Wt[n][k] + bias[n]),  A: MxK bf16, Wt: NxK bf16
// 128x128 tile, BK=32, 4 waves (2x2), wave 64x64 (4x4 16x16x32 frags).
// LDS logical layout: [128 rows][32 k] bf16 (64B rows); physical byte = logical ^ (((L>>7)&7)<<4)
// (XOR row-pair index into the 16B-slot bits -> 2 lanes/bank on ds_read_b128 = conflict-free).
// global_load_lds writes linearly -> global SOURCE address is inverse-swizzled per lane (rule 21).
__global__ __launch_bounds__(256) void gemm_mfma_kernel(
    const __hip_bfloat16* __restrict__ A,
    const __hip_bfloat16* __restrict__ Wt,
    const float* __restrict__ bias,
    __hip_bfloat16* __restrict__ C,
    int K, int N) {
    __shared__ __align__(16) __hip_bfloat16 Als[2][128 * 32];
    __shared__ __align__(16) __hip_bfloat16 Bls[2][128 * 32];
    const int tid = threadIdx.x;
    const int wave = tid >> 6, lane = tid & 63;
    const int m0 = blockIdx.x * 128, n0 = blockIdx.y * 128;
    const int wr = wave >> 1, wc = wave & 1;
    const int fr = lane & 15, fq = lane >> 4;

    // ---- per-lane staging coords (physical slot -> logical row/k via involution) ----
    int srow[2], skel[2], sofs[2];
#pragma unroll
    for (int j = 0; j < 2; ++j) {
        int P = (wave * 128 + j * 64 + lane) * 16;   // physical byte in 8KB tile
        int L = P ^ (((P >> 7) & 7) << 4);           // logical byte (involution)
        srow[j] = L >> 6;                            // logical row 0..127
        skel[j] = (L & 63) >> 1;                     // logical k element 0..31 (8-aligned)
        sofs[j] = wave * 2048 + j * 1024;            // wave-uniform LDS byte base
    }
    // ---- per-lane read offsets (elements), loop-invariant ----
    int aoff[4], boff[4];
#pragma unroll
    for (int mi = 0; mi < 4; ++mi) {
        int r = wr * 64 + mi * 16 + fr;
        int Lb = r * 64 + fq * 16;
        aoff[mi] = (Lb ^ (((r >> 1) & 7) << 4)) >> 1;
    }
#pragma unroll
    for (int ni = 0; ni < 4; ++ni) {
        int r = wc * 64 + ni * 16 + fr;
        int Lb = r * 64 + fq * 16;
        boff[ni] = (Lb ^ (((r >> 1) & 7) << 4)) >> 1;
    }

    f32x4 acc[4][4] = {};

    auto stage = [&](int kt, int buf) {
#pragma unroll
        for (int j = 0; j < 2; ++j) {
            GLD_LDS16(A + (size_t)(m0 + srow[j]) * K + kt + skel[j], (char*)Als[buf] + sofs[j]);
            GLD_LDS16(Wt + (size_t)(n0 + srow[j]) * K + kt + skel[j], (char*)Bls[buf] + sofs[j]);
        }
    };

    const int nt = K >> 5;
    stage(0, 0);                      // 4 vmem ops in flight
    for (int t = 0; t < nt; ++t) {
        const int cur = t & 1;
        if (t + 1 < nt) {
            stage((t + 1) << 5, cur ^ 1);   // issue next tile (4 more ops)
            SCHED_FENCE();
            ASM_VMCNT4();                   // wait my buf[cur] loads (newest 4 stay in flight)
        } else {
            ASM_VMCNT0();
        }
        SCHED_FENCE();
        __builtin_amdgcn_s_barrier();       // #1: everyone's buf[cur] staged
        bf16x8 av[4], bv[4];
#pragma unroll
        for (int mi = 0; mi < 4; ++mi)
            av[mi] = *reinterpret_cast<const bf16x8*>(Als[cur] + aoff[mi]);
#pragma unroll
        for (int ni = 0; ni < 4; ++ni)
            bv[ni] = *reinterpret_cast<const bf16x8*>(Bls[cur] + boff[ni]);
        ASM_LGKM0();                        // my ds_reads complete
        SCHED_FENCE();
        __builtin_amdgcn_s_barrier();       // #2: all reads done -> buf[cur] reusable next iter
#pragma unroll
        for (int mi = 0; mi < 4; ++mi)
#pragma unroll
            for (int ni = 0; ni < 4; ++ni)
                acc[mi][ni] = __builtin_amdgcn_mfma_f32_16x16x32_bf16(av[mi], bv[ni], acc[mi][ni], 0, 0, 0);
    }

    // epilogue: C/D layout col=lane&15, row=(lane>>4)*4+reg  [m89-verified]
#pragma unroll
    for (int mi = 0; mi < 4; ++mi) {
#pragma unroll
        for (int ni = 0; ni < 4; ++ni) {
            int n = n0 + wc * 64 + ni * 16 + fr;
            float bs = bias[n];
#pragma unroll
            for (int r = 0; r < 4; ++r) {
                int m = m0 + wr * 64 + mi * 16 + fq * 4 + r;
                float v = acc[mi][ni][r] + bs;
                C[(size_t)m * N + n] = __float2bfloat16(geluf(v));
            }
        }
    }
}

// ---------------- final layer (256->1) + sigmoid + coupling + twist update ----------------
__global__ __launch_bounds__(256) void tf_update_kernel(
    const __hip_bfloat16* __restrict__ h3,  // ROWS x 256
    const float* __restrict__ w4, const float* __restrict__ b4,
    const float* __restrict__ gf, const float* __restrict__ arp,
    float* __restrict__ out, __hip_bfloat16* __restrict__ outb) {
    const int wid = threadIdx.x >> 6, lane = threadIdx.x & 63;
    const int r = blockIdx.x * 4 + wid;
    const int b = r >> 12;  // S = 4096 rows per batch

    uint2 hv = reinterpret_cast<const uint2*>(h3 + (size_t)r * 256)[lane];
    __hip_bfloat16 hh[4];
    *reinterpret_cast<uint2*>(hh) = hv;
    float4 wv = reinterpret_cast<const float4*>(w4)[lane];
    float p = __bfloat162float(hh[0]) * wv.x + __bfloat162float(hh[1]) * wv.y +
              __bfloat162float(hh[2]) * wv.z + __bfloat162float(hh[3]) * wv.w;
#pragma unroll
    for (int off = 32; off; off >>= 1) p += __shfl_xor(p, off);
    float tf = sigmf_(p + b4[0]);
    float comb = 0.7f * gf[b] + 0.3f * tf;
    float c = BASE_COUPLING + arp[0] * (comb - 0.5f) * 2.0f;

    float4* row4 = reinterpret_cast<float4*>(out + (size_t)r * PD);
    uint2* rb4 = reinterpret_cast<uint2*>(outb + (size_t)r * PD);
    float4 o_r = row4[lane];
    float4 o_i = row4[64 + lane];
    float4 p_r = row4[128 + lane];
    float4 p_i = row4[192 + lane];
    float4 n0 = axpy4(o_r, c, p_r);
    float4 n1 = axpy4(o_i, -c, p_i);
    float4 n2 = axpy4(p_r, -c, o_r);
    float4 n3 = axpy4(p_i, c, o_i);
    row4[lane] = n0;        rb4[lane] = pk4(n0);
    row4[64 + lane] = n1;   rb4[64 + lane] = pk4(n1);
    row4[128 + lane] = n2;  rb4[128 + lane] = pk4(n2);
    row4[192 + lane] = n3;  rb4[192 + lane] = pk4(n3);
}

// ---------------- launch ----------------
extern "C" void kernel_launch(void* const* d_in, const int* in_sizes, int n_in,
                              void* d_out, int out_size, void* d_ws, size_t ws_size,
                              hipStream_t stream) {
    const float* x     = (const float*)d_in[0];
    const float* cn_w1 = (const float*)d_in[1];
    const float* cn_b1 = (const float*)d_in[2];
    const float* cn_w2 = (const float*)d_in[3];
    const float* cn_b2 = (const float*)d_in[4];
    const float* cn_w3 = (const float*)d_in[5];
    const float* cn_b3 = (const float*)d_in[6];
    const float* cn_w4 = (const float*)d_in[7];
    const float* cn_b4 = (const float*)d_in[8];
    const float* gc_w1 = (const float*)d_in[9];
    const float* gc_b1 = (const float*)d_in[10];
    const float* gc_w2 = (const float*)d_in[11];
    const float* gc_b2 = (const float*)d_in[12];
    const float* gc_w3 = (const float*)d_in[13];
    const float* gc_b3 = (const float*)d_in[14];
    const float* ar    = (const float*)d_in[15];

    float* out = (float*)d_out;

    char* ws = (char*)d_ws;
    __hip_bfloat16* h1   = (__hip_bfloat16*)(ws);                      // 32 MB
    __hip_bfloat16* h2   = (__hip_bfloat16*)(ws + ((size_t)32 << 20)); // 16 MB
    __hip_bfloat16* h3   = (__hip_bfloat16*)(ws + ((size_t)48 << 20)); // 8 MB
    __hip_bfloat16* outb = (__hip_bfloat16*)(ws + ((size_t)56 << 20)); // 32 MB
    __hip_bfloat16* wt1  = (__hip_bfloat16*)(ws + ((size_t)88 << 20)); // 2 MB
    __hip_bfloat16* wt2  = (__hip_bfloat16*)(ws + ((size_t)90 << 20)); // 1 MB
    __hip_bfloat16* wt3  = (__hip_bfloat16*)(ws + ((size_t)91 << 20)); // 0.25 MB
    float* part          = (float*)(ws + ((size_t)91 << 20) + (1 << 18)); // 4*64*1024 f32
    float* gc            = part + 4 * 64 * PD;
    float* g1            = gc + 4 * PD;
    float* g2            = g1 + 4 * 512;
    float* gf            = g2 + 4 * 256;

    transpose_w_kernel<<<dim3(32, 32), 256, 0, stream>>>(cn_w1, wt1, 1024, 1024);
    transpose_w_kernel<<<dim3(32, 16), 256, 0, stream>>>(cn_w2, wt2, 1024, 512);
    transpose_w_kernel<<<dim3(16, 8), 256, 0, stream>>>(cn_w3, wt3, 512, 256);

    copy_mean_kernel<<<256, 256, 0, stream>>>(x, out, outb, part);
    mean_stage2<<<PB, 256, 0, stream>>>(part, gc);

    gn1_kernel<<<dim3(PB, 8), 256, 0, stream>>>(gc, gc_w1, gc_b1, g1);
    gn2_kernel<<<dim3(PB, 4), 256, 0, stream>>>(g1, gc_w2, gc_b2, g2);
    gn3_kernel<<<PB, 256, 0, stream>>>(g2, gc_w3, gc_b3, gf);

    for (int cyc = 0; cyc < NUM_CYCLES; ++cyc) {
        gemm_mfma_kernel<<<dim3(ROWS / 128, 1024 / 128), 256, 0, stream>>>(
            outb, wt1, cn_b1, h1, 1024, 1024);
        gemm_mfma_kernel<<<dim3(ROWS / 128, 512 / 128), 256, 0, stream>>>(
            h1, wt2, cn_b2, h2, 1024, 512);
        gemm_mfma_kernel<<<dim3(ROWS / 128, 256 / 128), 256, 0, stream>>>(
            h2, wt3, cn_b3, h3, 512, 256);
        tf_update_kernel<<<ROWS / 4, 256, 0, stream>>>(h3, cn_w4, cn_b4, gf, ar, out, outb);
    }
}